// Round 12
// baseline (516.583 us; speedup 1.0000x reference)
//
#include <hip/hip_runtime.h>
#include <hip/hip_bf16.h>
#include <hip/hip_fp16.h>

typedef unsigned int uint32;
typedef unsigned short u16;

#define TOK 1024
#define HID 2048
#define NEXP 64
#define TOPK 8
#define IMED 768
#define IMED2 1536

typedef __attribute__((ext_vector_type(8))) _Float16 half8;
typedef __attribute__((ext_vector_type(4))) float f32x4;

static __device__ __forceinline__ uint32 pack2(float a, float b) {
  union { _Float16 h[2]; uint32 u; } p;
  p.h[0] = (_Float16)a; p.h[1] = (_Float16)b;
  return p.u;
}
static __device__ __forceinline__ u16 f2h(float a) {
  union { _Float16 h; u16 u; } p;
  p.h = (_Float16)a;
  return p.u;
}

// ---------------- router: 4 tokens/block; logits -> top8 -> renorm; emits xh
__global__ __launch_bounds__(256) void router_kernel(
    const float* __restrict__ x, const float* __restrict__ gw,
    int* __restrict__ topk_id, float* __restrict__ topk_w,
    u16* __restrict__ xh) {
  int t0 = blockIdx.x << 2;
  __shared__ float part[4][NEXP][5];
  int tid = threadIdx.x;
  int e = tid & 63, p = tid >> 6;
  const float* gwp = gw + (size_t)e * HID + (p << 9);
  const float* xp = x + (size_t)t0 * HID + (p << 9);
  float acc[4] = {0.f, 0.f, 0.f, 0.f};
  for (int i = 0; i < 128; i++) {
    float4 w = ((const float4*)gwp)[i];
    #pragma unroll
    for (int t = 0; t < 4; t++) {
      float4 xv = *(const float4*)(xp + (size_t)t * HID + (i << 2));
      acc[t] += w.x * xv.x + w.y * xv.y + w.z * xv.z + w.w * xv.w;
    }
  }
  #pragma unroll
  for (int t = 0; t < 4; t++) part[p][e][t] = acc[t];
  for (int i = tid; i < 2048; i += 256) {
    int r = i >> 9;
    int c = i & 511;
    float4 v = *(const float4*)(x + (size_t)(t0 + r) * HID + (c << 2));
    uint2 hp;
    hp.x = pack2(v.x, v.y);
    hp.y = pack2(v.z, v.w);
    *(uint2*)(xh + (size_t)(t0 + r) * HID + (c << 2)) = hp;
  }
  __syncthreads();
  int wv = tid >> 6, l = tid & 63;
  int t = t0 + wv;
  float lg = part[0][l][wv] + part[1][l][wv] + part[2][l][wv] + part[3][l][wv];
  float m = lg;
  #pragma unroll
  for (int d = 1; d < 64; d <<= 1) m = fmaxf(m, __shfl_xor(m, d));
  float v = __expf(lg - m);
  float w8[TOPK]; int i8[TOPK]; float wsum = 0.f;
  #pragma unroll
  for (int k = 0; k < TOPK; k++) {
    float bv = v; int bi = l;
    #pragma unroll
    for (int d = 1; d < 64; d <<= 1) {
      float ov = __shfl_xor(bv, d);
      int oi = __shfl_xor(bi, d);
      if (ov > bv || (ov == bv && oi < bi)) { bv = ov; bi = oi; }
    }
    w8[k] = bv; i8[k] = bi; wsum += bv;
    if (l == bi) v = -1.f;
  }
  if (l == 0) {
    float rinv = 1.f / wsum;
    #pragma unroll
    for (int k = 0; k < TOPK; k++) {
      topk_id[t * TOPK + k] = i8[k];
      topk_w[t * TOPK + k] = w8[k] * rinv;
    }
  }
}

// ------- per-expert scatter (64 blocks), self-counting; also zeroes done ---
__global__ __launch_bounds__(256) void scatter_kernel(
    const int* __restrict__ topk_id, const float* __restrict__ topk_w,
    int* __restrict__ off, int* __restrict__ gcnt,
    int* __restrict__ row_tok, float* __restrict__ row_w,
    int* __restrict__ done) {
  int e = blockIdx.x;
  __shared__ int lcnt[NEXP];
  __shared__ int sbase;
  __shared__ int scur;
  int tid = threadIdx.x;
  if (tid < NEXP) lcnt[tid] = 0;
  if (blockIdx.x == 0 && tid < NEXP) done[tid] = 0;
  __syncthreads();
  for (int i = tid; i < TOK * TOPK; i += 256) atomicAdd(&lcnt[topk_id[i]], 1);
  __syncthreads();
  if (tid < 64) {
    int c = lcnt[tid];
    int xv = c;
    #pragma unroll
    for (int d = 1; d < 64; d <<= 1) {
      int y = __shfl_up(xv, d);
      if (tid >= d) xv += y;
    }
    if (tid == e) {
      sbase = xv - c;
      off[e] = xv - c;
      gcnt[e] = c;
    }
    if (tid == 0) scur = 0;
  }
  __syncthreads();
  int base = sbase;
  for (int i = tid; i < TOK * TOPK; i += 256) {
    if (topk_id[i] == e) {
      int p = atomicAdd(&scur, 1);
      row_tok[base + p] = i >> 3;
      row_w[base + p] = topk_w[i];
    }
  }
}

// ------------- fused expert kernel: gateup (2 slabs) -> spin -> down (2 slabs)
// 256 blocks (1/CU, all co-resident), 512 threads.
// block = (xcd, expert-group, quad): e on its XCD; per-expert done[] barrier.
__global__ __launch_bounds__(512, 2) void moe_kernel(
    const u16* __restrict__ xh, const float* __restrict__ Wgu,
    const float* __restrict__ Wd, const int* __restrict__ off,
    const int* __restrict__ cnt, const int* __restrict__ row_tok,
    const float* __restrict__ row_w, u16* __restrict__ act,
    float* __restrict__ out, int* __restrict__ done) {
  int bid = blockIdx.x;                      // 256 blocks
  int xcd = bid & 7, eg = (bid >> 3) & 7, q = bid >> 6;  // q 0..3
  int e = xcd + (eg << 3);
  int r0 = off[e];
  int ne = cnt[e];

  __shared__ __align__(16) char LDS[40960];
  char* AsB = LDS;           // 20 KB (256 rows x 80B)
  char* BsB = LDS + 20480;   // gateup 15 KB / down 20 KB

  int tid = threadIdx.x;
  int lane = tid & 63;
  int wid = tid >> 6;
  int wm = wid >> 1, wn = wid & 1;
  int fr = lane & 15, hi = lane >> 4;

  int arow = tid >> 1, aseg = tid & 1;
  int axr = (arow >> 2) & 3;
  int tok = row_tok[r0 + ((arow < ne) ? arow : 0)];

  // ================= phase 1: gateup slabs q, q+4 =================
  {
    bool bact = tid < 384;
    int cg = tid % 24, h = (tid / 24) & 1, kq = tid / 48;
    int bcol = cg << 2;
    int brbase = 96 * h + bcol;

    for (int sl = 0; sl < 2; sl++) {
      int c0 = (q + (sl << 2)) * 96;
      const u16* xa = xh + (size_t)tok * HID + (aseg << 4);
      int gc = h ? (IMED + c0 + bcol) : (c0 + bcol);
      const float* wb = Wgu + (size_t)e * ((size_t)HID * IMED2) +
                        (size_t)(kq << 2) * IMED2 + gc;

      f32x4 accg[4][3], accu[4][3];
      #pragma unroll
      for (int a = 0; a < 4; a++)
        #pragma unroll
        for (int b = 0; b < 3; b++) { accg[a][b] = (f32x4)0.f; accu[a][b] = (f32x4)0.f; }

      uint4 qa0, qa1;
      float4 w0, w1, w2, w3;
      auto LOADT = [&]() {
        const uint4* p = (const uint4*)xa;
        qa0 = p[0]; qa1 = p[1];
        xa += 32;
        if (bact) {
          w0 = *(const float4*)(wb);
          w1 = *(const float4*)(wb + IMED2);
          w2 = *(const float4*)(wb + 2 * IMED2);
          w3 = *(const float4*)(wb + 3 * IMED2);
        }
        wb += (size_t)32 * IMED2;
      };
      auto STORET = [&]() {
        char* A_ = AsB + arow * 80;
        int g0 = aseg << 1;
        *(uint4*)(A_ + (((g0 + 0) ^ axr) << 4)) = qa0;
        *(uint4*)(A_ + (((g0 + 1) ^ axr) << 4)) = qa1;
        if (bact) {
          float c0v[4] = {w0.x, w0.y, w0.z, w0.w};
          float c1v[4] = {w1.x, w1.y, w1.z, w1.w};
          float c2v[4] = {w2.x, w2.y, w2.z, w2.w};
          float c3v[4] = {w3.x, w3.y, w3.z, w3.w};
          int kg = kq >> 1, kb = (kq & 1) << 3;
          #pragma unroll
          for (int cc = 0; cc < 4; cc++) {
            int br = brbase + cc;
            uint2 pv;
            pv.x = pack2(c0v[cc], c1v[cc]);
            pv.y = pack2(c2v[cc], c3v[cc]);
            *(uint2*)(BsB + br * 80 + (((kg ^ (br >> 2)) & 3) << 4) + kb) = pv;
          }
        }
      };

      const int NK = HID / 32;  // 64
      LOADT();
      STORET();
      LOADT();
      __syncthreads();

      for (int t = 0; t < NK; ++t) {
        half8 af[4];
        #pragma unroll
        for (int mi = 0; mi < 4; mi++) {
          int r = (wm << 6) + (mi << 4) + fr;
          af[mi] = *(half8*)(AsB + r * 80 + (((hi ^ (r >> 2)) & 3) << 4));
        }
        #pragma unroll
        for (int ni = 0; ni < 3; ni++) {
          int ng = (wn * 48) + (ni << 4) + fr;
          int nu = ng + 96;
          half8 bg = *(half8*)(BsB + ng * 80 + (((hi ^ (ng >> 2)) & 3) << 4));
          half8 bu = *(half8*)(BsB + nu * 80 + (((hi ^ (nu >> 2)) & 3) << 4));
          #pragma unroll
          for (int mi = 0; mi < 4; mi++) {
            accg[mi][ni] = __builtin_amdgcn_mfma_f32_16x16x32_f16(af[mi], bg, accg[mi][ni], 0, 0, 0);
            accu[mi][ni] = __builtin_amdgcn_mfma_f32_16x16x32_f16(af[mi], bu, accu[mi][ni], 0, 0, 0);
          }
        }
        __syncthreads();
        if (t + 1 < NK) {
          STORET();
          if (t + 2 < NK) LOADT();
          __syncthreads();
        }
      }

      #pragma unroll
      for (int mi = 0; mi < 4; mi++) {
        #pragma unroll
        for (int ni = 0; ni < 3; ni++) {
          int col = c0 + wn * 48 + (ni << 4) + fr;
          #pragma unroll
          for (int r = 0; r < 4; r++) {
            int rr = (wm << 6) + (mi << 4) + (hi << 2) + r;
            if (rr < ne) {
              float g = accg[mi][ni][r];
              float u = accu[mi][ni][r];
              float s = g / (1.f + __expf(-g)) * u;
              act[(size_t)(r0 + rr) * IMED + col] = f2h(s);
            }
          }
        }
      }
      __syncthreads();  // LDS safe for next slab
    }
  }

  // ================= per-expert barrier =================
  __threadfence();
  __syncthreads();
  if (tid == 0) {
    atomicAdd(&done[e], 1);
    while (__hip_atomic_load(done + e, __ATOMIC_ACQUIRE, __HIP_MEMORY_SCOPE_AGENT) < 4) {
    }
  }
  __syncthreads();
  __threadfence();

  // ================= phase 2: down slabs q, q+4 =================
  {
    int cq = tid & 63, kq = tid >> 6;
    int bcol = cq << 2;

    for (int sl = 0; sl < 2; sl++) {
      int n0 = (q + (sl << 2)) << 8;
      const u16* ap = act + (size_t)(r0 + ((arow < ne) ? arow : 0)) * IMED + (aseg << 4);
      const float* wb = Wd + (size_t)e * ((size_t)IMED * HID) +
                        (size_t)(kq << 2) * HID + n0 + bcol;

      f32x4 acc[4][8];
      #pragma unroll
      for (int a = 0; a < 4; a++)
        #pragma unroll
        for (int b = 0; b < 8; b++) acc[a][b] = (f32x4)0.f;

      uint4 qa0, qa1;
      float4 w0, w1, w2, w3;
      auto LOADT = [&]() {
        const uint4* p = (const uint4*)ap;
        qa0 = p[0]; qa1 = p[1];
        ap += 32;
        w0 = *(const float4*)(wb);
        w1 = *(const float4*)(wb + HID);
        w2 = *(const float4*)(wb + 2 * HID);
        w3 = *(const float4*)(wb + 3 * HID);
        wb += (size_t)32 * HID;
      };
      auto STORET = [&]() {
        char* A_ = AsB + arow * 80;
        int g0 = aseg << 1;
        *(uint4*)(A_ + (((g0 + 0) ^ axr) << 4)) = qa0;
        *(uint4*)(A_ + (((g0 + 1) ^ axr) << 4)) = qa1;
        float c0v[4] = {w0.x, w0.y, w0.z, w0.w};
        float c1v[4] = {w1.x, w1.y, w1.z, w1.w};
        float c2v[4] = {w2.x, w2.y, w2.z, w2.w};
        float c3v[4] = {w3.x, w3.y, w3.z, w3.w};
        int kg = kq >> 1, kb = (kq & 1) << 3;
        #pragma unroll
        for (int cc = 0; cc < 4; cc++) {
          int br = bcol + cc;
          uint2 pv;
          pv.x = pack2(c0v[cc], c1v[cc]);
          pv.y = pack2(c2v[cc], c3v[cc]);
          *(uint2*)(BsB + br * 80 + (((kg ^ (br >> 2)) & 3) << 4) + kb) = pv;
        }
      };

      const int NK = IMED / 32;  // 24
      LOADT();
      STORET();
      LOADT();
      __syncthreads();

      for (int t = 0; t < NK; ++t) {
        half8 af[4];
        #pragma unroll
        for (int mi = 0; mi < 4; mi++) {
          int r = (wm << 6) + (mi << 4) + fr;
          af[mi] = *(half8*)(AsB + r * 80 + (((hi ^ (r >> 2)) & 3) << 4));
        }
        #pragma unroll
        for (int ni = 0; ni < 8; ni++) {
          int n = (wn << 7) + (ni << 4) + fr;
          half8 bf_ = *(half8*)(BsB + n * 80 + (((hi ^ (n >> 2)) & 3) << 4));
          #pragma unroll
          for (int mi = 0; mi < 4; mi++)
            acc[mi][ni] = __builtin_amdgcn_mfma_f32_16x16x32_f16(af[mi], bf_, acc[mi][ni], 0, 0, 0);
        }
        __syncthreads();
        if (t + 1 < NK) {
          STORET();
          if (t + 2 < NK) LOADT();
          __syncthreads();
        }
      }

      #pragma unroll
      for (int mi = 0; mi < 4; mi++) {
        #pragma unroll
        for (int r = 0; r < 4; r++) {
          int rr = (wm << 6) + (mi << 4) + (hi << 2) + r;
          if (rr < ne) {
            float w = row_w[r0 + rr];
            int t = row_tok[r0 + rr];
            #pragma unroll
            for (int ni = 0; ni < 8; ni++) {
              int col = n0 + (wn << 7) + (ni << 4) + fr;
              unsafeAtomicAdd(&out[(size_t)t * HID + col], acc[mi][ni][r] * w);
            }
          }
        }
      }
      __syncthreads();  // LDS safe for next slab
    }
  }
}

// ---------------- launch ----------------
extern "C" void kernel_launch(void* const* d_in, const int* in_sizes, int n_in,
                              void* d_out, int out_size, void* d_ws, size_t ws_size,
                              hipStream_t stream) {
  const float* x = (const float*)d_in[0];
  const float* gw = (const float*)d_in[1];
  const float* wgu = (const float*)d_in[2];
  const float* wd = (const float*)d_in[3];
  float* out = (float*)d_out;
  char* ws = (char*)d_ws;

  int* gcnt = (int*)(ws + 0);
  int* off = (int*)(ws + 512);
  int* done = (int*)(ws + 768);
  int* topk_id = (int*)(ws + 1024);
  float* topk_w = (float*)(ws + 1024 + 32768);
  int* row_tok = (int*)(ws + 1024 + 65536);
  float* row_w = (float*)(ws + 1024 + 98304);
  u16* act = (u16*)(ws + 135168);                                   // 12.6 MB
  u16* xh = (u16*)(ws + 135168 + 12582912);                         // 4 MB

  router_kernel<<<TOK / 4, 256, 0, stream>>>(x, gw, topk_id, topk_w, xh);
  scatter_kernel<<<NEXP, 256, 0, stream>>>(topk_id, topk_w, off, gcnt, row_tok, row_w, done);
  (void)hipMemsetAsync(out, 0, (size_t)TOK * HID * sizeof(float), stream);
  moe_kernel<<<256, 512, 0, stream>>>(xh, wgu, wd, off, gcnt, row_tok, row_w, act, out, done);
}

// Round 13
// 369.113 us; speedup vs baseline: 1.3995x; 1.3995x over previous
//
#include <hip/hip_runtime.h>
#include <hip/hip_bf16.h>
#include <hip/hip_fp16.h>

typedef unsigned int uint32;
typedef unsigned short u16;

#define TOK 1024
#define HID 2048
#define NEXP 64
#define TOPK 8
#define IMED 768
#define IMED2 1536
#define LSTR 112  // LDS row stride (bytes): 28 words -> conflict-free b128 at row stride

typedef __attribute__((ext_vector_type(8))) _Float16 half8;
typedef __attribute__((ext_vector_type(4))) float f32x4;

static __device__ __forceinline__ uint32 pack2(float a, float b) {
  union { _Float16 h[2]; uint32 u; } p;
  p.h[0] = (_Float16)a; p.h[1] = (_Float16)b;
  return p.u;
}
static __device__ __forceinline__ u16 f2h(float a) {
  union { _Float16 h; u16 u; } p;
  p.h = (_Float16)a;
  return p.u;
}

// ---------------- router: 4 tokens/block; logits -> top8 -> renorm; emits xh
__global__ __launch_bounds__(256) void router_kernel(
    const float* __restrict__ x, const float* __restrict__ gw,
    int* __restrict__ topk_id, float* __restrict__ topk_w,
    u16* __restrict__ xh) {
  int t0 = blockIdx.x << 2;
  __shared__ float part[4][NEXP][5];
  int tid = threadIdx.x;
  int e = tid & 63, p = tid >> 6;
  const float* gwp = gw + (size_t)e * HID + (p << 9);
  const float* xp = x + (size_t)t0 * HID + (p << 9);
  float acc[4] = {0.f, 0.f, 0.f, 0.f};
  for (int i = 0; i < 128; i++) {
    float4 w = ((const float4*)gwp)[i];
    #pragma unroll
    for (int t = 0; t < 4; t++) {
      float4 xv = *(const float4*)(xp + (size_t)t * HID + (i << 2));
      acc[t] += w.x * xv.x + w.y * xv.y + w.z * xv.z + w.w * xv.w;
    }
  }
  #pragma unroll
  for (int t = 0; t < 4; t++) part[p][e][t] = acc[t];
  for (int i = tid; i < 2048; i += 256) {
    int r = i >> 9;
    int c = i & 511;
    float4 v = *(const float4*)(x + (size_t)(t0 + r) * HID + (c << 2));
    uint2 hp;
    hp.x = pack2(v.x, v.y);
    hp.y = pack2(v.z, v.w);
    *(uint2*)(xh + (size_t)(t0 + r) * HID + (c << 2)) = hp;
  }
  __syncthreads();
  int wv = tid >> 6, l = tid & 63;
  int t = t0 + wv;
  float lg = part[0][l][wv] + part[1][l][wv] + part[2][l][wv] + part[3][l][wv];
  float m = lg;
  #pragma unroll
  for (int d = 1; d < 64; d <<= 1) m = fmaxf(m, __shfl_xor(m, d));
  float v = __expf(lg - m);
  float w8[TOPK]; int i8[TOPK]; float wsum = 0.f;
  #pragma unroll
  for (int k = 0; k < TOPK; k++) {
    float bv = v; int bi = l;
    #pragma unroll
    for (int d = 1; d < 64; d <<= 1) {
      float ov = __shfl_xor(bv, d);
      int oi = __shfl_xor(bi, d);
      if (ov > bv || (ov == bv && oi < bi)) { bv = ov; bi = oi; }
    }
    w8[k] = bv; i8[k] = bi; wsum += bv;
    if (l == bi) v = -1.f;
  }
  if (l == 0) {
    float rinv = 1.f / wsum;
    #pragma unroll
    for (int k = 0; k < TOPK; k++) {
      topk_id[t * TOPK + k] = i8[k];
      topk_w[t * TOPK + k] = w8[k] * rinv;
    }
  }
}

// ------- per-expert scatter (64 blocks), self-counting, no memset ----------
__global__ __launch_bounds__(256) void scatter_kernel(
    const int* __restrict__ topk_id, const float* __restrict__ topk_w,
    int* __restrict__ off, int* __restrict__ gcnt,
    int* __restrict__ row_tok, float* __restrict__ row_w,
    int* __restrict__ inv) {
  int e = blockIdx.x;
  __shared__ int lcnt[NEXP];
  __shared__ int sbase;
  __shared__ int scur;
  int tid = threadIdx.x;
  if (tid < NEXP) lcnt[tid] = 0;
  __syncthreads();
  for (int i = tid; i < TOK * TOPK; i += 256) atomicAdd(&lcnt[topk_id[i]], 1);
  __syncthreads();
  if (tid < 64) {
    int c = lcnt[tid];
    int xv = c;
    #pragma unroll
    for (int d = 1; d < 64; d <<= 1) {
      int y = __shfl_up(xv, d);
      if (tid >= d) xv += y;
    }
    if (tid == e) {
      sbase = xv - c;
      off[e] = xv - c;
      gcnt[e] = c;
    }
    if (tid == 0) scur = 0;
  }
  __syncthreads();
  int base = sbase;
  for (int i = tid; i < TOK * TOPK; i += 256) {
    if (topk_id[i] == e) {
      int p = atomicAdd(&scur, 1);
      row_tok[base + p] = i >> 3;
      row_w[base + p] = topk_w[i];
      inv[i] = base + p;
    }
  }
}

// ---------------- grouped gate_up GEMM + fused SwiGLU ----------------
// BM=256, BN=96 gate + 96 up, BK=32, 512 threads (8 waves 4m x 2n)
// single LDS buffer (stride-112 conflict-free), 1-deep register prefetch
__global__ __launch_bounds__(512, 2) void gateup_kernel(
    const u16* __restrict__ xh, const float* __restrict__ Wgu,
    const int* __restrict__ off, const int* __restrict__ cnt,
    const int* __restrict__ row_tok, u16* __restrict__ act) {
  int bid = blockIdx.x;                 // 512 blocks
  int xcd = bid & 7, s2 = bid >> 3;
  int e = xcd + ((s2 & 7) << 3);        // all slabs of expert e on one XCD
  int slab = s2 >> 3;                   // 0..7
  int r0 = off[e];
  int ne = cnt[e];
  int c0 = slab * 96;

  __shared__ __align__(16) char AsB[256 * LSTR];  // 28 KB
  __shared__ __align__(16) char BsB[192 * LSTR];  // 21 KB

  int tid = threadIdx.x;
  int lane = tid & 63;
  int wid = tid >> 6;
  int wm = wid >> 1, wn = wid & 1;      // 4m x 2n
  int fr = lane & 15, hi = lane >> 4;

  // A stage: 2 threads/row, 16 f16 (2 granules) each
  int arow = tid >> 1, aseg = tid & 1;
  int tok = row_tok[r0 + ((arow < ne) ? arow : 0)];
  const u16* xa = xh + (size_t)tok * HID + (aseg << 4);

  // B stage: 384 threads; thread -> 1 col x 16 k (half the K-step)
  bool bact = tid < 384;
  int bc = tid % 192;                   // local col 0..191 (0..95 gate, 96..191 up)
  int bkh = tid / 192;                  // 0..1 (k-half)
  int gcol = (bc < 96) ? (c0 + bc) : (IMED + c0 + (bc - 96));
  const float* wb = Wgu + (size_t)e * ((size_t)HID * IMED2) +
                    (size_t)(bkh << 4) * IMED2 + gcol;

  f32x4 accg[4][3], accu[4][3];
  #pragma unroll
  for (int a = 0; a < 4; a++)
    #pragma unroll
    for (int b = 0; b < 3; b++) { accg[a][b] = (f32x4)0.f; accu[a][b] = (f32x4)0.f; }

  uint4 qa0, qa1;
  float wv[16];
  auto LOADT = [&]() {
    const uint4* p = (const uint4*)xa;
    qa0 = p[0]; qa1 = p[1];
    xa += 32;
    if (bact) {
      #pragma unroll
      for (int j = 0; j < 16; j++) wv[j] = wb[(size_t)j * IMED2];
    }
    wb += (size_t)32 * IMED2;
  };
  auto STORET = [&]() {
    char* A_ = AsB + arow * LSTR + (aseg << 5);
    *(uint4*)(A_) = qa0;
    *(uint4*)(A_ + 16) = qa1;
    if (bact) {
      uint4 u0, u1;
      u0.x = pack2(wv[0], wv[1]);  u0.y = pack2(wv[2], wv[3]);
      u0.z = pack2(wv[4], wv[5]);  u0.w = pack2(wv[6], wv[7]);
      u1.x = pack2(wv[8], wv[9]);  u1.y = pack2(wv[10], wv[11]);
      u1.z = pack2(wv[12], wv[13]); u1.w = pack2(wv[14], wv[15]);
      char* B_ = BsB + bc * LSTR + (bkh << 5);
      *(uint4*)(B_) = u0;
      *(uint4*)(B_ + 16) = u1;
    }
  };

  const int NK = HID / 32;  // 64
  LOADT();
  STORET();
  LOADT();
  __syncthreads();

  for (int t = 0; t < NK; ++t) {
    half8 af[4];
    #pragma unroll
    for (int mi = 0; mi < 4; mi++) {
      int r = (wm << 6) + (mi << 4) + fr;
      af[mi] = *(half8*)(AsB + r * LSTR + (hi << 4));
    }
    #pragma unroll
    for (int ni = 0; ni < 3; ni++) {
      int ng = (wn * 48) + (ni << 4) + fr;
      half8 bg = *(half8*)(BsB + ng * LSTR + (hi << 4));
      half8 bu = *(half8*)(BsB + (ng + 96) * LSTR + (hi << 4));
      #pragma unroll
      for (int mi = 0; mi < 4; mi++) {
        accg[mi][ni] = __builtin_amdgcn_mfma_f32_16x16x32_f16(af[mi], bg, accg[mi][ni], 0, 0, 0);
        accu[mi][ni] = __builtin_amdgcn_mfma_f32_16x16x32_f16(af[mi], bu, accu[mi][ni], 0, 0, 0);
      }
    }
    __syncthreads();
    if (t + 1 < NK) {
      STORET();
      if (t + 2 < NK) LOADT();
      __syncthreads();
    }
  }

  #pragma unroll
  for (int mi = 0; mi < 4; mi++) {
    #pragma unroll
    for (int ni = 0; ni < 3; ni++) {
      int col = c0 + wn * 48 + (ni << 4) + fr;
      #pragma unroll
      for (int r = 0; r < 4; r++) {
        int rr = (wm << 6) + (mi << 4) + (hi << 2) + r;
        if (rr < ne) {
          float g = accg[mi][ni][r];
          float u = accu[mi][ni][r];
          float s = g / (1.f + __expf(-g)) * u;
          act[(size_t)(r0 + rr) * IMED + col] = f2h(s);
        }
      }
    }
  }
}

// ---------------- grouped down GEMM -> f16 scratch (no atomics) ------------
// BM=256, BN=256, BK=32, 512 threads (8 waves 4m x 2n), stride-112 LDS
__global__ __launch_bounds__(512, 2) void down_kernel(
    const u16* __restrict__ act, const float* __restrict__ Wd,
    const int* __restrict__ off, const int* __restrict__ cnt,
    const float* __restrict__ row_w, u16* __restrict__ dscr) {
  int bid = blockIdx.x;                 // 512 blocks
  int xcd = bid & 7, s2 = bid >> 3;
  int e = xcd + ((s2 & 7) << 3);
  int slab = s2 >> 3;                   // 0..7
  int r0 = off[e];
  int ne = cnt[e];
  int n0 = slab << 8;

  __shared__ __align__(16) char AsB[256 * LSTR];  // 28 KB
  __shared__ __align__(16) char BsB[256 * LSTR];  // 28 KB

  int tid = threadIdx.x;
  int lane = tid & 63;
  int wid = tid >> 6;
  int wm = wid >> 1, wn = wid & 1;
  int fr = lane & 15, hi = lane >> 4;

  int arow = tid >> 1, aseg = tid & 1;
  const u16* ap = act + (size_t)(r0 + ((arow < ne) ? arow : 0)) * IMED + (aseg << 4);

  // B stage: thread -> 1 col x 16 k
  int bcn = tid & 255;                  // col 0..255
  int bkh = tid >> 8;                   // 0..1
  const float* wb = Wd + (size_t)e * ((size_t)IMED * HID) +
                    (size_t)(bkh << 4) * HID + n0 + bcn;

  f32x4 acc[4][8];
  #pragma unroll
  for (int a = 0; a < 4; a++)
    #pragma unroll
    for (int b = 0; b < 8; b++) acc[a][b] = (f32x4)0.f;

  uint4 qa0, qa1;
  float wv[16];
  auto LOADT = [&]() {
    const uint4* p = (const uint4*)ap;
    qa0 = p[0]; qa1 = p[1];
    ap += 32;
    #pragma unroll
    for (int j = 0; j < 16; j++) wv[j] = wb[(size_t)j * HID];
    wb += (size_t)32 * HID;
  };
  auto STORET = [&]() {
    char* A_ = AsB + arow * LSTR + (aseg << 5);
    *(uint4*)(A_) = qa0;
    *(uint4*)(A_ + 16) = qa1;
    uint4 u0, u1;
    u0.x = pack2(wv[0], wv[1]);  u0.y = pack2(wv[2], wv[3]);
    u0.z = pack2(wv[4], wv[5]);  u0.w = pack2(wv[6], wv[7]);
    u1.x = pack2(wv[8], wv[9]);  u1.y = pack2(wv[10], wv[11]);
    u1.z = pack2(wv[12], wv[13]); u1.w = pack2(wv[14], wv[15]);
    char* B_ = BsB + bcn * LSTR + (bkh << 5);
    *(uint4*)(B_) = u0;
    *(uint4*)(B_ + 16) = u1;
  };

  const int NK = IMED / 32;  // 24
  LOADT();
  STORET();
  LOADT();
  __syncthreads();

  for (int t = 0; t < NK; ++t) {
    half8 af[4];
    #pragma unroll
    for (int mi = 0; mi < 4; mi++) {
      int r = (wm << 6) + (mi << 4) + fr;
      af[mi] = *(half8*)(AsB + r * LSTR + (hi << 4));
    }
    #pragma unroll
    for (int ni = 0; ni < 8; ni++) {
      int n = (wn << 7) + (ni << 4) + fr;
      half8 bf_ = *(half8*)(BsB + n * LSTR + (hi << 4));
      #pragma unroll
      for (int mi = 0; mi < 4; mi++)
        acc[mi][ni] = __builtin_amdgcn_mfma_f32_16x16x32_f16(af[mi], bf_, acc[mi][ni], 0, 0, 0);
    }
    __syncthreads();
    if (t + 1 < NK) {
      STORET();
      if (t + 2 < NK) LOADT();
      __syncthreads();
    }
  }

  #pragma unroll
  for (int mi = 0; mi < 4; mi++) {
    #pragma unroll
    for (int r = 0; r < 4; r++) {
      int rr = (wm << 6) + (mi << 4) + (hi << 2) + r;
      if (rr < ne) {
        float w = row_w[r0 + rr];
        #pragma unroll
        for (int ni = 0; ni < 8; ni++) {
          int col = n0 + (wn << 7) + (ni << 4) + fr;
          dscr[(size_t)(r0 + rr) * HID + col] = f2h(acc[mi][ni][r] * w);
        }
      }
    }
  }
}

// ---------------- combine: out[t] = sum_k dscr[inv[t*8+k]] ------------------
__global__ __launch_bounds__(256) void combine_kernel(
    const u16* __restrict__ dscr, const int* __restrict__ inv,
    float* __restrict__ out) {
  int t = blockIdx.x;
  int c0 = threadIdx.x << 3;  // 8 cols per thread
  int rows[TOPK];
  #pragma unroll
  for (int k = 0; k < TOPK; k++) rows[k] = inv[t * TOPK + k];
  float s[8] = {0.f, 0.f, 0.f, 0.f, 0.f, 0.f, 0.f, 0.f};
  #pragma unroll
  for (int k = 0; k < TOPK; k++) {
    union { uint4 q; _Float16 h[8]; } u;
    u.q = *(const uint4*)(dscr + (size_t)rows[k] * HID + c0);
    #pragma unroll
    for (int j = 0; j < 8; j++) s[j] += (float)u.h[j];
  }
  float4 o0 = {s[0], s[1], s[2], s[3]};
  float4 o1 = {s[4], s[5], s[6], s[7]};
  *(float4*)(out + (size_t)t * HID + c0) = o0;
  *(float4*)(out + (size_t)t * HID + c0 + 4) = o1;
}

// ---------------- launch ----------------
extern "C" void kernel_launch(void* const* d_in, const int* in_sizes, int n_in,
                              void* d_out, int out_size, void* d_ws, size_t ws_size,
                              hipStream_t stream) {
  const float* x = (const float*)d_in[0];
  const float* gw = (const float*)d_in[1];
  const float* wgu = (const float*)d_in[2];
  const float* wd = (const float*)d_in[3];
  float* out = (float*)d_out;
  char* ws = (char*)d_ws;

  int* gcnt = (int*)(ws + 0);
  int* off = (int*)(ws + 512);
  int* topk_id = (int*)(ws + 1024);
  float* topk_w = (float*)(ws + 1024 + 32768);
  int* row_tok = (int*)(ws + 1024 + 65536);
  float* row_w = (float*)(ws + 1024 + 98304);
  u16* act = (u16*)(ws + 135168);                                   // 12.6 MB
  u16* xh = (u16*)(ws + 135168 + 12582912);                         // 4 MB
  int* inv = (int*)(ws + 135168 + 12582912 + 4194304);              // 32 KB
  u16* dscr = (u16*)(ws + 135168 + 12582912 + 4194304 + 32768);     // 33.5 MB

  router_kernel<<<TOK / 4, 256, 0, stream>>>(x, gw, topk_id, topk_w, xh);
  scatter_kernel<<<NEXP, 256, 0, stream>>>(topk_id, topk_w, off, gcnt, row_tok, row_w, inv);
  gateup_kernel<<<512, 512, 0, stream>>>(xh, wgu, off, gcnt, row_tok, act);
  down_kernel<<<512, 512, 0, stream>>>(act, wd, off, gcnt, row_w, dscr);
  combine_kernel<<<TOK, 256, 0, stream>>>(dscr, inv, out);
}

// Round 14
// 367.633 us; speedup vs baseline: 1.4052x; 1.0040x over previous
//
#include <hip/hip_runtime.h>
#include <hip/hip_bf16.h>
#include <hip/hip_fp16.h>

typedef unsigned int uint32;
typedef unsigned short u16;

#define TOK 1024
#define HID 2048
#define NEXP 64
#define TOPK 8
#define IMED 768
#define IMED2 1536
#define LSTR 112  // LDS row stride (bytes): 28 words -> conflict-free b128 reads

typedef __attribute__((ext_vector_type(8))) _Float16 half8;
typedef __attribute__((ext_vector_type(4))) float f32x4;

static __device__ __forceinline__ uint32 pack2(float a, float b) {
  union { _Float16 h[2]; uint32 u; } p;
  p.h[0] = (_Float16)a; p.h[1] = (_Float16)b;
  return p.u;
}
static __device__ __forceinline__ u16 f2h(float a) {
  union { _Float16 h; u16 u; } p;
  p.h = (_Float16)a;
  return p.u;
}

// ---------------- router: 4 tokens/block; logits -> top8 -> renorm; emits xh
__global__ __launch_bounds__(256) void router_kernel(
    const float* __restrict__ x, const float* __restrict__ gw,
    int* __restrict__ topk_id, float* __restrict__ topk_w,
    u16* __restrict__ xh) {
  int t0 = blockIdx.x << 2;
  __shared__ float part[4][NEXP][5];
  int tid = threadIdx.x;
  int e = tid & 63, p = tid >> 6;
  const float* gwp = gw + (size_t)e * HID + (p << 9);
  const float* xp = x + (size_t)t0 * HID + (p << 9);
  float acc[4] = {0.f, 0.f, 0.f, 0.f};
  for (int i = 0; i < 128; i++) {
    float4 w = ((const float4*)gwp)[i];
    #pragma unroll
    for (int t = 0; t < 4; t++) {
      float4 xv = *(const float4*)(xp + (size_t)t * HID + (i << 2));
      acc[t] += w.x * xv.x + w.y * xv.y + w.z * xv.z + w.w * xv.w;
    }
  }
  #pragma unroll
  for (int t = 0; t < 4; t++) part[p][e][t] = acc[t];
  for (int i = tid; i < 2048; i += 256) {
    int r = i >> 9;
    int c = i & 511;
    float4 v = *(const float4*)(x + (size_t)(t0 + r) * HID + (c << 2));
    uint2 hp;
    hp.x = pack2(v.x, v.y);
    hp.y = pack2(v.z, v.w);
    *(uint2*)(xh + (size_t)(t0 + r) * HID + (c << 2)) = hp;
  }
  __syncthreads();
  int wv = tid >> 6, l = tid & 63;
  int t = t0 + wv;
  float lg = part[0][l][wv] + part[1][l][wv] + part[2][l][wv] + part[3][l][wv];
  float m = lg;
  #pragma unroll
  for (int d = 1; d < 64; d <<= 1) m = fmaxf(m, __shfl_xor(m, d));
  float v = __expf(lg - m);
  float w8[TOPK]; int i8[TOPK]; float wsum = 0.f;
  #pragma unroll
  for (int k = 0; k < TOPK; k++) {
    float bv = v; int bi = l;
    #pragma unroll
    for (int d = 1; d < 64; d <<= 1) {
      float ov = __shfl_xor(bv, d);
      int oi = __shfl_xor(bi, d);
      if (ov > bv || (ov == bv && oi < bi)) { bv = ov; bi = oi; }
    }
    w8[k] = bv; i8[k] = bi; wsum += bv;
    if (l == bi) v = -1.f;
  }
  if (l == 0) {
    float rinv = 1.f / wsum;
    #pragma unroll
    for (int k = 0; k < TOPK; k++) {
      topk_id[t * TOPK + k] = i8[k];
      topk_w[t * TOPK + k] = w8[k] * rinv;
    }
  }
}

// ------- per-expert scatter (64 blocks), self-counting, no memset ----------
__global__ __launch_bounds__(256) void scatter_kernel(
    const int* __restrict__ topk_id, const float* __restrict__ topk_w,
    int* __restrict__ off, int* __restrict__ gcnt,
    int* __restrict__ row_tok, float* __restrict__ row_w,
    int* __restrict__ inv) {
  int e = blockIdx.x;
  __shared__ int lcnt[NEXP];
  __shared__ int sbase;
  __shared__ int scur;
  int tid = threadIdx.x;
  if (tid < NEXP) lcnt[tid] = 0;
  __syncthreads();
  for (int i = tid; i < TOK * TOPK; i += 256) atomicAdd(&lcnt[topk_id[i]], 1);
  __syncthreads();
  if (tid < 64) {
    int c = lcnt[tid];
    int xv = c;
    #pragma unroll
    for (int d = 1; d < 64; d <<= 1) {
      int y = __shfl_up(xv, d);
      if (tid >= d) xv += y;
    }
    if (tid == e) {
      sbase = xv - c;
      off[e] = xv - c;
      gcnt[e] = c;
    }
    if (tid == 0) scur = 0;
  }
  __syncthreads();
  int base = sbase;
  for (int i = tid; i < TOK * TOPK; i += 256) {
    if (topk_id[i] == e) {
      int p = atomicAdd(&scur, 1);
      row_tok[base + p] = i >> 3;
      row_w[base + p] = topk_w[i];
      inv[i] = base + p;
    }
  }
}

// ---------------- grouped gate_up GEMM + fused SwiGLU ----------------
// BM=256, BN=96 gate + 96 up, BK=32, 512 threads (8 waves 4m x 2n)
// stride-112 LDS, A 1-deep + B 2-deep register prefetch
__global__ __launch_bounds__(512, 2) void gateup_kernel(
    const u16* __restrict__ xh, const float* __restrict__ Wgu,
    const int* __restrict__ off, const int* __restrict__ cnt,
    const int* __restrict__ row_tok, u16* __restrict__ act) {
  int bid = blockIdx.x;                 // 512 blocks
  int xcd = bid & 7, s2 = bid >> 3;
  int e = xcd + ((s2 & 7) << 3);
  int slab = s2 >> 3;                   // 0..7
  int r0 = off[e];
  int ne = cnt[e];
  int c0 = slab * 96;

  __shared__ __align__(16) char AsB[256 * LSTR];  // 28 KB
  __shared__ __align__(16) char BsB[192 * LSTR];  // 21 KB

  int tid = threadIdx.x;
  int lane = tid & 63;
  int wid = tid >> 6;
  int wm = wid >> 1, wn = wid & 1;
  int fr = lane & 15, hi = lane >> 4;

  // A stage: 2 threads/row, 16 f16 (2 granules) each
  int arow = tid >> 1, aseg = tid & 1;
  int tok = row_tok[r0 + ((arow < ne) ? arow : 0)];
  const u16* xa = xh + (size_t)tok * HID + (aseg << 4);

  // B stage: 384 threads; thread -> 1 col x 16 k
  bool bact = tid < 384;
  int bc = tid % 192;
  int bkh = tid / 192;
  int gcol = (bc < 96) ? (c0 + bc) : (IMED + c0 + (bc - 96));
  const float* wb = Wgu + (size_t)e * ((size_t)HID * IMED2) +
                    (size_t)(bkh << 4) * IMED2 + gcol;

  f32x4 accg[4][3], accu[4][3];
  #pragma unroll
  for (int a = 0; a < 4; a++)
    #pragma unroll
    for (int b = 0; b < 3; b++) { accg[a][b] = (f32x4)0.f; accu[a][b] = (f32x4)0.f; }

  uint4 qa0, qa1;
  float wv0[16], wv1[16];
  auto LOADA = [&]() {
    const uint4* p = (const uint4*)xa;
    qa0 = p[0]; qa1 = p[1];
    xa += 32;
  };
  auto LOADB = [&](float* wv) {
    if (bact) {
      #pragma unroll
      for (int j = 0; j < 16; j++) wv[j] = wb[(size_t)j * IMED2];
    }
    wb += (size_t)32 * IMED2;
  };
  auto STORET = [&](const float* wv) {
    char* A_ = AsB + arow * LSTR + (aseg << 5);
    *(uint4*)(A_) = qa0;
    *(uint4*)(A_ + 16) = qa1;
    if (bact) {
      uint4 u0, u1;
      u0.x = pack2(wv[0], wv[1]);  u0.y = pack2(wv[2], wv[3]);
      u0.z = pack2(wv[4], wv[5]);  u0.w = pack2(wv[6], wv[7]);
      u1.x = pack2(wv[8], wv[9]);  u1.y = pack2(wv[10], wv[11]);
      u1.z = pack2(wv[12], wv[13]); u1.w = pack2(wv[14], wv[15]);
      char* B_ = BsB + bc * LSTR + (bkh << 5);
      *(uint4*)(B_) = u0;
      *(uint4*)(B_ + 16) = u1;
    }
  };
  auto COMPUTE = [&]() {
    half8 af[4];
    #pragma unroll
    for (int mi = 0; mi < 4; mi++) {
      int r = (wm << 6) + (mi << 4) + fr;
      af[mi] = *(half8*)(AsB + r * LSTR + (hi << 4));
    }
    #pragma unroll
    for (int ni = 0; ni < 3; ni++) {
      int ng = (wn * 48) + (ni << 4) + fr;
      half8 bg = *(half8*)(BsB + ng * LSTR + (hi << 4));
      half8 bu = *(half8*)(BsB + (ng + 96) * LSTR + (hi << 4));
      #pragma unroll
      for (int mi = 0; mi < 4; mi++) {
        accg[mi][ni] = __builtin_amdgcn_mfma_f32_16x16x32_f16(af[mi], bg, accg[mi][ni], 0, 0, 0);
        accu[mi][ni] = __builtin_amdgcn_mfma_f32_16x16x32_f16(af[mi], bu, accu[mi][ni], 0, 0, 0);
      }
    }
  };

  const int NK = HID / 32;  // 64 (even)
  // prologue: set0 <- t0; store t0; A <- t1; set1 <- t1; set0 <- t2
  LOADA(); LOADB(wv0);
  STORET(wv0);
  LOADA(); LOADB(wv1);
  LOADB(wv0);
  __syncthreads();

  for (int t = 0; t < NK; t += 2) {
    COMPUTE();                               // tile t
    __syncthreads();
    if (t + 1 < NK) {
      STORET(wv1);                           // tile t+1
      if (t + 2 < NK) LOADA();               // A t+2
      if (t + 3 < NK) LOADB(wv1);            // B t+3
      __syncthreads();
    }
    if (t + 1 < NK) {
      COMPUTE();                             // tile t+1
      __syncthreads();
      if (t + 2 < NK) {
        STORET(wv0);                         // tile t+2
        if (t + 3 < NK) LOADA();             // A t+3
        if (t + 4 < NK) LOADB(wv0);          // B t+4
        __syncthreads();
      }
    }
  }

  #pragma unroll
  for (int mi = 0; mi < 4; mi++) {
    #pragma unroll
    for (int ni = 0; ni < 3; ni++) {
      int col = c0 + wn * 48 + (ni << 4) + fr;
      #pragma unroll
      for (int r = 0; r < 4; r++) {
        int rr = (wm << 6) + (mi << 4) + (hi << 2) + r;
        if (rr < ne) {
          float g = accg[mi][ni][r];
          float u = accu[mi][ni][r];
          float s = g / (1.f + __expf(-g)) * u;
          act[(size_t)(r0 + rr) * IMED + col] = f2h(s);
        }
      }
    }
  }
}

// ---------------- grouped down GEMM -> f16 scratch (no atomics) ------------
// BM=256, BN=256, BK=32, 512 threads, stride-112 LDS, B 2-deep prefetch
__global__ __launch_bounds__(512, 2) void down_kernel(
    const u16* __restrict__ act, const float* __restrict__ Wd,
    const int* __restrict__ off, const int* __restrict__ cnt,
    const float* __restrict__ row_w, u16* __restrict__ dscr) {
  int bid = blockIdx.x;                 // 512 blocks
  int xcd = bid & 7, s2 = bid >> 3;
  int e = xcd + ((s2 & 7) << 3);
  int slab = s2 >> 3;                   // 0..7
  int r0 = off[e];
  int ne = cnt[e];
  int n0 = slab << 8;

  __shared__ __align__(16) char AsB[256 * LSTR];  // 28 KB
  __shared__ __align__(16) char BsB[256 * LSTR];  // 28 KB

  int tid = threadIdx.x;
  int lane = tid & 63;
  int wid = tid >> 6;
  int wm = wid >> 1, wn = wid & 1;
  int fr = lane & 15, hi = lane >> 4;

  int arow = tid >> 1, aseg = tid & 1;
  const u16* ap = act + (size_t)(r0 + ((arow < ne) ? arow : 0)) * IMED + (aseg << 4);

  int bcn = tid & 255;
  int bkh = tid >> 8;
  const float* wb = Wd + (size_t)e * ((size_t)IMED * HID) +
                    (size_t)(bkh << 4) * HID + n0 + bcn;

  f32x4 acc[4][8];
  #pragma unroll
  for (int a = 0; a < 4; a++)
    #pragma unroll
    for (int b = 0; b < 8; b++) acc[a][b] = (f32x4)0.f;

  uint4 qa0, qa1;
  float wv0[16], wv1[16];
  auto LOADA = [&]() {
    const uint4* p = (const uint4*)ap;
    qa0 = p[0]; qa1 = p[1];
    ap += 32;
  };
  auto LOADB = [&](float* wv) {
    #pragma unroll
    for (int j = 0; j < 16; j++) wv[j] = wb[(size_t)j * HID];
    wb += (size_t)32 * HID;
  };
  auto STORET = [&](const float* wv) {
    char* A_ = AsB + arow * LSTR + (aseg << 5);
    *(uint4*)(A_) = qa0;
    *(uint4*)(A_ + 16) = qa1;
    uint4 u0, u1;
    u0.x = pack2(wv[0], wv[1]);  u0.y = pack2(wv[2], wv[3]);
    u0.z = pack2(wv[4], wv[5]);  u0.w = pack2(wv[6], wv[7]);
    u1.x = pack2(wv[8], wv[9]);  u1.y = pack2(wv[10], wv[11]);
    u1.z = pack2(wv[12], wv[13]); u1.w = pack2(wv[14], wv[15]);
    char* B_ = BsB + bcn * LSTR + (bkh << 5);
    *(uint4*)(B_) = u0;
    *(uint4*)(B_ + 16) = u1;
  };
  auto COMPUTE = [&]() {
    half8 af[4];
    #pragma unroll
    for (int mi = 0; mi < 4; mi++) {
      int r = (wm << 6) + (mi << 4) + fr;
      af[mi] = *(half8*)(AsB + r * LSTR + (hi << 4));
    }
    #pragma unroll
    for (int ni = 0; ni < 8; ni++) {
      int n = (wn << 7) + (ni << 4) + fr;
      half8 bf_ = *(half8*)(BsB + n * LSTR + (hi << 4));
      #pragma unroll
      for (int mi = 0; mi < 4; mi++)
        acc[mi][ni] = __builtin_amdgcn_mfma_f32_16x16x32_f16(af[mi], bf_, acc[mi][ni], 0, 0, 0);
    }
  };

  const int NK = IMED / 32;  // 24 (even)
  LOADA(); LOADB(wv0);
  STORET(wv0);
  LOADA(); LOADB(wv1);
  LOADB(wv0);
  __syncthreads();

  for (int t = 0; t < NK; t += 2) {
    COMPUTE();                               // tile t
    __syncthreads();
    if (t + 1 < NK) {
      STORET(wv1);                           // tile t+1
      if (t + 2 < NK) LOADA();
      if (t + 3 < NK) LOADB(wv1);
      __syncthreads();
    }
    if (t + 1 < NK) {
      COMPUTE();                             // tile t+1
      __syncthreads();
      if (t + 2 < NK) {
        STORET(wv0);                         // tile t+2
        if (t + 3 < NK) LOADA();
        if (t + 4 < NK) LOADB(wv0);
        __syncthreads();
      }
    }
  }

  #pragma unroll
  for (int mi = 0; mi < 4; mi++) {
    #pragma unroll
    for (int r = 0; r < 4; r++) {
      int rr = (wm << 6) + (mi << 4) + (hi << 2) + r;
      if (rr < ne) {
        float w = row_w[r0 + rr];
        #pragma unroll
        for (int ni = 0; ni < 8; ni++) {
          int col = n0 + (wn << 7) + (ni << 4) + fr;
          dscr[(size_t)(r0 + rr) * HID + col] = f2h(acc[mi][ni][r] * w);
        }
      }
    }
  }
}

// ---------------- combine: out[t] = sum_k dscr[inv[t*8+k]] ------------------
__global__ __launch_bounds__(256) void combine_kernel(
    const u16* __restrict__ dscr, const int* __restrict__ inv,
    float* __restrict__ out) {
  int t = blockIdx.x;
  int c0 = threadIdx.x << 3;
  int rows[TOPK];
  #pragma unroll
  for (int k = 0; k < TOPK; k++) rows[k] = inv[t * TOPK + k];
  float s[8] = {0.f, 0.f, 0.f, 0.f, 0.f, 0.f, 0.f, 0.f};
  #pragma unroll
  for (int k = 0; k < TOPK; k++) {
    union { uint4 q; _Float16 h[8]; } u;
    u.q = *(const uint4*)(dscr + (size_t)rows[k] * HID + c0);
    #pragma unroll
    for (int j = 0; j < 8; j++) s[j] += (float)u.h[j];
  }
  float4 o0 = {s[0], s[1], s[2], s[3]};
  float4 o1 = {s[4], s[5], s[6], s[7]};
  *(float4*)(out + (size_t)t * HID + c0) = o0;
  *(float4*)(out + (size_t)t * HID + c0 + 4) = o1;
}

// ---------------- launch ----------------
extern "C" void kernel_launch(void* const* d_in, const int* in_sizes, int n_in,
                              void* d_out, int out_size, void* d_ws, size_t ws_size,
                              hipStream_t stream) {
  const float* x = (const float*)d_in[0];
  const float* gw = (const float*)d_in[1];
  const float* wgu = (const float*)d_in[2];
  const float* wd = (const float*)d_in[3];
  float* out = (float*)d_out;
  char* ws = (char*)d_ws;

  int* gcnt = (int*)(ws + 0);
  int* off = (int*)(ws + 512);
  int* topk_id = (int*)(ws + 1024);
  float* topk_w = (float*)(ws + 1024 + 32768);
  int* row_tok = (int*)(ws + 1024 + 65536);
  float* row_w = (float*)(ws + 1024 + 98304);
  u16* act = (u16*)(ws + 135168);                                   // 12.6 MB
  u16* xh = (u16*)(ws + 135168 + 12582912);                         // 4 MB
  int* inv = (int*)(ws + 135168 + 12582912 + 4194304);              // 32 KB
  u16* dscr = (u16*)(ws + 135168 + 12582912 + 4194304 + 32768);     // 33.5 MB

  router_kernel<<<TOK / 4, 256, 0, stream>>>(x, gw, topk_id, topk_w, xh);
  scatter_kernel<<<NEXP, 256, 0, stream>>>(topk_id, topk_w, off, gcnt, row_tok, row_w, inv);
  gateup_kernel<<<512, 512, 0, stream>>>(xh, wgu, off, gcnt, row_tok, act);
  down_kernel<<<512, 512, 0, stream>>>(act, wd, off, gcnt, row_w, dscr);
  combine_kernel<<<TOK, 256, 0, stream>>>(dscr, inv, out);
}

// Round 15
// 364.920 us; speedup vs baseline: 1.4156x; 1.0074x over previous
//
#include <hip/hip_runtime.h>
#include <hip/hip_bf16.h>
#include <hip/hip_fp16.h>

typedef unsigned int uint32;
typedef unsigned short u16;

#define TOK 1024
#define HID 2048
#define NEXP 64
#define TOPK 8
#define IMED 768
#define IMED2 1536
#define LSTR 112  // LDS row stride (bytes): 28 words -> conflict-free b128 reads

typedef __attribute__((ext_vector_type(8))) _Float16 half8;
typedef __attribute__((ext_vector_type(4))) float f32x4;

static __device__ __forceinline__ uint32 pack2(float a, float b) {
  union { _Float16 h[2]; uint32 u; } p;
  p.h[0] = (_Float16)a; p.h[1] = (_Float16)b;
  return p.u;
}
static __device__ __forceinline__ u16 f2h(float a) {
  union { _Float16 h; u16 u; } p;
  p.h = (_Float16)a;
  return p.u;
}
// Barrier WITHOUT vmcnt drain: waits only this wave's LDS ops, then raw
// s_barrier. Outstanding global loads ride across; their waits are emitted
// at the register-consumption site (counted vmcnt), not here.
static __device__ __forceinline__ void bar_nodrain() {
  asm volatile("s_waitcnt lgkmcnt(0)" ::: "memory");
  __builtin_amdgcn_sched_barrier(0);
  __builtin_amdgcn_s_barrier();
}

// ---------------- router: 4 tokens/block; logits -> top8 -> renorm; emits xh
__global__ __launch_bounds__(256) void router_kernel(
    const float* __restrict__ x, const float* __restrict__ gw,
    int* __restrict__ topk_id, float* __restrict__ topk_w,
    u16* __restrict__ xh) {
  int t0 = blockIdx.x << 2;
  __shared__ float part[4][NEXP][5];
  int tid = threadIdx.x;
  int e = tid & 63, p = tid >> 6;
  const float* gwp = gw + (size_t)e * HID + (p << 9);
  const float* xp = x + (size_t)t0 * HID + (p << 9);
  float acc[4] = {0.f, 0.f, 0.f, 0.f};
  for (int i = 0; i < 128; i++) {
    float4 w = ((const float4*)gwp)[i];
    #pragma unroll
    for (int t = 0; t < 4; t++) {
      float4 xv = *(const float4*)(xp + (size_t)t * HID + (i << 2));
      acc[t] += w.x * xv.x + w.y * xv.y + w.z * xv.z + w.w * xv.w;
    }
  }
  #pragma unroll
  for (int t = 0; t < 4; t++) part[p][e][t] = acc[t];
  for (int i = tid; i < 2048; i += 256) {
    int r = i >> 9;
    int c = i & 511;
    float4 v = *(const float4*)(x + (size_t)(t0 + r) * HID + (c << 2));
    uint2 hp;
    hp.x = pack2(v.x, v.y);
    hp.y = pack2(v.z, v.w);
    *(uint2*)(xh + (size_t)(t0 + r) * HID + (c << 2)) = hp;
  }
  __syncthreads();
  int wv = tid >> 6, l = tid & 63;
  int t = t0 + wv;
  float lg = part[0][l][wv] + part[1][l][wv] + part[2][l][wv] + part[3][l][wv];
  float m = lg;
  #pragma unroll
  for (int d = 1; d < 64; d <<= 1) m = fmaxf(m, __shfl_xor(m, d));
  float v = __expf(lg - m);
  float w8[TOPK]; int i8[TOPK]; float wsum = 0.f;
  #pragma unroll
  for (int k = 0; k < TOPK; k++) {
    float bv = v; int bi = l;
    #pragma unroll
    for (int d = 1; d < 64; d <<= 1) {
      float ov = __shfl_xor(bv, d);
      int oi = __shfl_xor(bi, d);
      if (ov > bv || (ov == bv && oi < bi)) { bv = ov; bi = oi; }
    }
    w8[k] = bv; i8[k] = bi; wsum += bv;
    if (l == bi) v = -1.f;
  }
  if (l == 0) {
    float rinv = 1.f / wsum;
    #pragma unroll
    for (int k = 0; k < TOPK; k++) {
      topk_id[t * TOPK + k] = i8[k];
      topk_w[t * TOPK + k] = w8[k] * rinv;
    }
  }
}

// ------- per-expert scatter (64 blocks), self-counting, no memset ----------
__global__ __launch_bounds__(256) void scatter_kernel(
    const int* __restrict__ topk_id, const float* __restrict__ topk_w,
    int* __restrict__ off, int* __restrict__ gcnt,
    int* __restrict__ row_tok, float* __restrict__ row_w,
    int* __restrict__ inv) {
  int e = blockIdx.x;
  __shared__ int lcnt[NEXP];
  __shared__ int sbase;
  __shared__ int scur;
  int tid = threadIdx.x;
  if (tid < NEXP) lcnt[tid] = 0;
  __syncthreads();
  for (int i = tid; i < TOK * TOPK; i += 256) atomicAdd(&lcnt[topk_id[i]], 1);
  __syncthreads();
  if (tid < 64) {
    int c = lcnt[tid];
    int xv = c;
    #pragma unroll
    for (int d = 1; d < 64; d <<= 1) {
      int y = __shfl_up(xv, d);
      if (tid >= d) xv += y;
    }
    if (tid == e) {
      sbase = xv - c;
      off[e] = xv - c;
      gcnt[e] = c;
    }
    if (tid == 0) scur = 0;
  }
  __syncthreads();
  int base = sbase;
  for (int i = tid; i < TOK * TOPK; i += 256) {
    if (topk_id[i] == e) {
      int p = atomicAdd(&scur, 1);
      row_tok[base + p] = i >> 3;
      row_w[base + p] = topk_w[i];
      inv[i] = base + p;
    }
  }
}

// ---------------- grouped gate_up GEMM + fused SwiGLU ----------------
// BM=256, BN=96 gate + 96 up, BK=32, 512 threads (8 waves 4m x 2n)
// stride-112 LDS, A 1-deep + B 2-deep register prefetch, non-draining barriers
__global__ __launch_bounds__(512, 2) void gateup_kernel(
    const u16* __restrict__ xh, const float* __restrict__ Wgu,
    const int* __restrict__ off, const int* __restrict__ cnt,
    const int* __restrict__ row_tok, u16* __restrict__ act) {
  int bid = blockIdx.x;                 // 512 blocks
  int xcd = bid & 7, s2 = bid >> 3;
  int e = xcd + ((s2 & 7) << 3);
  int slab = s2 >> 3;                   // 0..7
  int r0 = off[e];
  int ne = cnt[e];
  int c0 = slab * 96;

  __shared__ __align__(16) char AsB[256 * LSTR];  // 28 KB
  __shared__ __align__(16) char BsB[192 * LSTR];  // 21 KB

  int tid = threadIdx.x;
  int lane = tid & 63;
  int wid = tid >> 6;
  int wm = wid >> 1, wn = wid & 1;
  int fr = lane & 15, hi = lane >> 4;

  // A stage: 2 threads/row, 16 f16 (2 granules) each
  int arow = tid >> 1, aseg = tid & 1;
  int tok = row_tok[r0 + ((arow < ne) ? arow : 0)];
  const u16* xa = xh + (size_t)tok * HID + (aseg << 4);

  // B stage: 384 threads; thread -> 1 col x 16 k
  bool bact = tid < 384;
  int bc = tid % 192;
  int bkh = tid / 192;
  int gcol = (bc < 96) ? (c0 + bc) : (IMED + c0 + (bc - 96));
  const float* wb = Wgu + (size_t)e * ((size_t)HID * IMED2) +
                    (size_t)(bkh << 4) * IMED2 + gcol;

  f32x4 accg[4][3], accu[4][3];
  #pragma unroll
  for (int a = 0; a < 4; a++)
    #pragma unroll
    for (int b = 0; b < 3; b++) { accg[a][b] = (f32x4)0.f; accu[a][b] = (f32x4)0.f; }

  uint4 qa0, qa1;
  float wv0[16], wv1[16];
  auto LOADA = [&]() {
    const uint4* p = (const uint4*)xa;
    qa0 = p[0]; qa1 = p[1];
    xa += 32;
  };
  auto LOADB = [&](float* wv) {
    if (bact) {
      #pragma unroll
      for (int j = 0; j < 16; j++) wv[j] = wb[(size_t)j * IMED2];
    }
    wb += (size_t)32 * IMED2;
  };
  auto STORET = [&](const float* wv) {
    char* A_ = AsB + arow * LSTR + (aseg << 5);
    *(uint4*)(A_) = qa0;
    *(uint4*)(A_ + 16) = qa1;
    if (bact) {
      uint4 u0, u1;
      u0.x = pack2(wv[0], wv[1]);  u0.y = pack2(wv[2], wv[3]);
      u0.z = pack2(wv[4], wv[5]);  u0.w = pack2(wv[6], wv[7]);
      u1.x = pack2(wv[8], wv[9]);  u1.y = pack2(wv[10], wv[11]);
      u1.z = pack2(wv[12], wv[13]); u1.w = pack2(wv[14], wv[15]);
      char* B_ = BsB + bc * LSTR + (bkh << 5);
      *(uint4*)(B_) = u0;
      *(uint4*)(B_ + 16) = u1;
    }
  };
  auto COMPUTE = [&]() {
    half8 af[4];
    #pragma unroll
    for (int mi = 0; mi < 4; mi++) {
      int r = (wm << 6) + (mi << 4) + fr;
      af[mi] = *(half8*)(AsB + r * LSTR + (hi << 4));
    }
    #pragma unroll
    for (int ni = 0; ni < 3; ni++) {
      int ng = (wn * 48) + (ni << 4) + fr;
      half8 bg = *(half8*)(BsB + ng * LSTR + (hi << 4));
      half8 bu = *(half8*)(BsB + (ng + 96) * LSTR + (hi << 4));
      #pragma unroll
      for (int mi = 0; mi < 4; mi++) {
        accg[mi][ni] = __builtin_amdgcn_mfma_f32_16x16x32_f16(af[mi], bg, accg[mi][ni], 0, 0, 0);
        accu[mi][ni] = __builtin_amdgcn_mfma_f32_16x16x32_f16(af[mi], bu, accu[mi][ni], 0, 0, 0);
      }
    }
  };

  const int NK = HID / 32;  // 64 (even)
  LOADA(); LOADB(wv0);
  STORET(wv0);
  LOADA(); LOADB(wv1);
  LOADB(wv0);
  __syncthreads();

  for (int t = 0; t < NK; t += 2) {
    COMPUTE();                               // tile t
    bar_nodrain();
    if (t + 1 < NK) {
      STORET(wv1);                           // tile t+1
      if (t + 2 < NK) LOADA();               // A t+2
      if (t + 3 < NK) LOADB(wv1);            // B t+3
      bar_nodrain();
    }
    if (t + 1 < NK) {
      COMPUTE();                             // tile t+1
      bar_nodrain();
      if (t + 2 < NK) {
        STORET(wv0);                         // tile t+2
        if (t + 3 < NK) LOADA();             // A t+3
        if (t + 4 < NK) LOADB(wv0);          // B t+4
        bar_nodrain();
      }
    }
  }

  #pragma unroll
  for (int mi = 0; mi < 4; mi++) {
    #pragma unroll
    for (int ni = 0; ni < 3; ni++) {
      int col = c0 + wn * 48 + (ni << 4) + fr;
      #pragma unroll
      for (int r = 0; r < 4; r++) {
        int rr = (wm << 6) + (mi << 4) + (hi << 2) + r;
        if (rr < ne) {
          float g = accg[mi][ni][r];
          float u = accu[mi][ni][r];
          float s = g / (1.f + __expf(-g)) * u;
          act[(size_t)(r0 + rr) * IMED + col] = f2h(s);
        }
      }
    }
  }
}

// ---------------- grouped down GEMM -> f16 scratch (no atomics) ------------
// BM=256, BN=256, BK=32, 512 threads, stride-112 LDS, B 2-deep prefetch,
// non-draining barriers
__global__ __launch_bounds__(512, 2) void down_kernel(
    const u16* __restrict__ act, const float* __restrict__ Wd,
    const int* __restrict__ off, const int* __restrict__ cnt,
    const float* __restrict__ row_w, u16* __restrict__ dscr) {
  int bid = blockIdx.x;                 // 512 blocks
  int xcd = bid & 7, s2 = bid >> 3;
  int e = xcd + ((s2 & 7) << 3);
  int slab = s2 >> 3;                   // 0..7
  int r0 = off[e];
  int ne = cnt[e];
  int n0 = slab << 8;

  __shared__ __align__(16) char AsB[256 * LSTR];  // 28 KB
  __shared__ __align__(16) char BsB[256 * LSTR];  // 28 KB

  int tid = threadIdx.x;
  int lane = tid & 63;
  int wid = tid >> 6;
  int wm = wid >> 1, wn = wid & 1;
  int fr = lane & 15, hi = lane >> 4;

  int arow = tid >> 1, aseg = tid & 1;
  const u16* ap = act + (size_t)(r0 + ((arow < ne) ? arow : 0)) * IMED + (aseg << 4);

  int bcn = tid & 255;
  int bkh = tid >> 8;
  const float* wb = Wd + (size_t)e * ((size_t)IMED * HID) +
                    (size_t)(bkh << 4) * HID + n0 + bcn;

  f32x4 acc[4][8];
  #pragma unroll
  for (int a = 0; a < 4; a++)
    #pragma unroll
    for (int b = 0; b < 8; b++) acc[a][b] = (f32x4)0.f;

  uint4 qa0, qa1;
  float wv0[16], wv1[16];
  auto LOADA = [&]() {
    const uint4* p = (const uint4*)ap;
    qa0 = p[0]; qa1 = p[1];
    ap += 32;
  };
  auto LOADB = [&](float* wv) {
    #pragma unroll
    for (int j = 0; j < 16; j++) wv[j] = wb[(size_t)j * HID];
    wb += (size_t)32 * HID;
  };
  auto STORET = [&](const float* wv) {
    char* A_ = AsB + arow * LSTR + (aseg << 5);
    *(uint4*)(A_) = qa0;
    *(uint4*)(A_ + 16) = qa1;
    uint4 u0, u1;
    u0.x = pack2(wv[0], wv[1]);  u0.y = pack2(wv[2], wv[3]);
    u0.z = pack2(wv[4], wv[5]);  u0.w = pack2(wv[6], wv[7]);
    u1.x = pack2(wv[8], wv[9]);  u1.y = pack2(wv[10], wv[11]);
    u1.z = pack2(wv[12], wv[13]); u1.w = pack2(wv[14], wv[15]);
    char* B_ = BsB + bcn * LSTR + (bkh << 5);
    *(uint4*)(B_) = u0;
    *(uint4*)(B_ + 16) = u1;
  };
  auto COMPUTE = [&]() {
    half8 af[4];
    #pragma unroll
    for (int mi = 0; mi < 4; mi++) {
      int r = (wm << 6) + (mi << 4) + fr;
      af[mi] = *(half8*)(AsB + r * LSTR + (hi << 4));
    }
    #pragma unroll
    for (int ni = 0; ni < 8; ni++) {
      int n = (wn << 7) + (ni << 4) + fr;
      half8 bf_ = *(half8*)(BsB + n * LSTR + (hi << 4));
      #pragma unroll
      for (int mi = 0; mi < 4; mi++)
        acc[mi][ni] = __builtin_amdgcn_mfma_f32_16x16x32_f16(af[mi], bf_, acc[mi][ni], 0, 0, 0);
    }
  };

  const int NK = IMED / 32;  // 24 (even)
  LOADA(); LOADB(wv0);
  STORET(wv0);
  LOADA(); LOADB(wv1);
  LOADB(wv0);
  __syncthreads();

  for (int t = 0; t < NK; t += 2) {
    COMPUTE();                               // tile t
    bar_nodrain();
    if (t + 1 < NK) {
      STORET(wv1);                           // tile t+1
      if (t + 2 < NK) LOADA();
      if (t + 3 < NK) LOADB(wv1);
      bar_nodrain();
    }
    if (t + 1 < NK) {
      COMPUTE();                             // tile t+1
      bar_nodrain();
      if (t + 2 < NK) {
        STORET(wv0);                         // tile t+2
        if (t + 3 < NK) LOADA();
        if (t + 4 < NK) LOADB(wv0);
        bar_nodrain();
      }
    }
  }

  #pragma unroll
  for (int mi = 0; mi < 4; mi++) {
    #pragma unroll
    for (int r = 0; r < 4; r++) {
      int rr = (wm << 6) + (mi << 4) + (hi << 2) + r;
      if (rr < ne) {
        float w = row_w[r0 + rr];
        #pragma unroll
        for (int ni = 0; ni < 8; ni++) {
          int col = n0 + (wn << 7) + (ni << 4) + fr;
          dscr[(size_t)(r0 + rr) * HID + col] = f2h(acc[mi][ni][r] * w);
        }
      }
    }
  }
}

// ---------------- combine: out[t] = sum_k dscr[inv[t*8+k]] ------------------
__global__ __launch_bounds__(256) void combine_kernel(
    const u16* __restrict__ dscr, const int* __restrict__ inv,
    float* __restrict__ out) {
  int t = blockIdx.x;
  int c0 = threadIdx.x << 3;
  int rows[TOPK];
  #pragma unroll
  for (int k = 0; k < TOPK; k++) rows[k] = inv[t * TOPK + k];
  float s[8] = {0.f, 0.f, 0.f, 0.f, 0.f, 0.f, 0.f, 0.f};
  #pragma unroll
  for (int k = 0; k < TOPK; k++) {
    union { uint4 q; _Float16 h[8]; } u;
    u.q = *(const uint4*)(dscr + (size_t)rows[k] * HID + c0);
    #pragma unroll
    for (int j = 0; j < 8; j++) s[j] += (float)u.h[j];
  }
  float4 o0 = {s[0], s[1], s[2], s[3]};
  float4 o1 = {s[4], s[5], s[6], s[7]};
  *(float4*)(out + (size_t)t * HID + c0) = o0;
  *(float4*)(out + (size_t)t * HID + c0 + 4) = o1;
}

// ---------------- launch ----------------
extern "C" void kernel_launch(void* const* d_in, const int* in_sizes, int n_in,
                              void* d_out, int out_size, void* d_ws, size_t ws_size,
                              hipStream_t stream) {
  const float* x = (const float*)d_in[0];
  const float* gw = (const float*)d_in[1];
  const float* wgu = (const float*)d_in[2];
  const float* wd = (const float*)d_in[3];
  float* out = (float*)d_out;
  char* ws = (char*)d_ws;

  int* gcnt = (int*)(ws + 0);
  int* off = (int*)(ws + 512);
  int* topk_id = (int*)(ws + 1024);
  float* topk_w = (float*)(ws + 1024 + 32768);
  int* row_tok = (int*)(ws + 1024 + 65536);
  float* row_w = (float*)(ws + 1024 + 98304);
  u16* act = (u16*)(ws + 135168);                                   // 12.6 MB
  u16* xh = (u16*)(ws + 135168 + 12582912);                         // 4 MB
  int* inv = (int*)(ws + 135168 + 12582912 + 4194304);              // 32 KB
  u16* dscr = (u16*)(ws + 135168 + 12582912 + 4194304 + 32768);     // 33.5 MB

  router_kernel<<<TOK / 4, 256, 0, stream>>>(x, gw, topk_id, topk_w, xh);
  scatter_kernel<<<NEXP, 256, 0, stream>>>(topk_id, topk_w, off, gcnt, row_tok, row_w, inv);
  gateup_kernel<<<512, 512, 0, stream>>>(xh, wgu, off, gcnt, row_tok, act);
  down_kernel<<<512, 512, 0, stream>>>(act, wd, off, gcnt, row_w, dscr);
  combine_kernel<<<TOK, 256, 0, stream>>>(dscr, inv, out);
}